// Round 12
// baseline (93.762 us; speedup 1.0000x reference)
//
#include <hip/hip_runtime.h>
#include <hip/hip_fp16.h>

#define N_NODES 50000
#define N_EDGES 800000
#define CH 64
#define FT_NODES 32
#define FT_BLKS ((N_NODES + FT_NODES - 1) / FT_NODES)   // 1563
#define NB 782                                          // bins = ceil(N/64) (64-node buckets)
#define NCHK 784                                        // edge chunks (hist blocks in k_feat)
#define ECHUNK ((N_EDGES + NCHK - 1) / NCHK)            // 1021
#define LCAP 3072                                       // per-bucket LDS edge cap (mean 1024, sigma 32)

static constexpr size_t alignup16(size_t x) { return (x + 15) & ~(size_t)15; }
// ---------------- ws layout (byte offsets, 16B-aligned) ----------------
static const size_t OFF_H    = 0;                                          // N*CH half (6.4 MB)
static const size_t OFF_SSRC = alignup16(OFF_H    + (size_t)N_NODES*CH*2);
static const size_t OFF_SDST = alignup16(OFF_SSRC + (size_t)N_NODES*4);
static const size_t OFF_HIST = alignup16(OFF_SDST + (size_t)N_NODES*4);    // NCHK*NB u32 [chunk][bin]
static const size_t OFF_BTOT = alignup16(OFF_HIST + (size_t)NCHK*NB*4);    // NB u32
static const size_t OFF_CB   = alignup16(OFF_BTOT + (size_t)NB*4);         // NB+1 u32
static const size_t OFF_BUCK = alignup16(OFF_CB   + (size_t)(NB+1)*4);     // E u32 (3.2 MB)

// K1: h = x @ W (fp16 out); s_src/s_dst scores; blocks < NCHK also histogram their
// edge chunk by bin (dst>>6) into LDS -> hist[blk][bin] (coalesced row write).
__global__ __launch_bounds__(256) void k_feat(
        const float* __restrict__ x, const float* __restrict__ W,
        const float* __restrict__ a_src, const float* __restrict__ a_dst,
        const int* __restrict__ edst,
        __half* __restrict__ h, float* __restrict__ ssrc, float* __restrict__ sdst,
        unsigned int* __restrict__ hist) {
    __shared__ float Ws[64 * 64];          // 16 KB
    __shared__ float xs[FT_NODES][68];
    __shared__ unsigned int lh[NB];        // 3.1 KB
    const int tid = threadIdx.x;
    const bool do_hist = (blockIdx.x < NCHK);
    if (do_hist)
        for (int j = tid; j < NB; j += 256) lh[j] = 0u;
#pragma unroll
    for (int i = 0; i < 16; ++i) Ws[tid + i * 256] = W[tid + i * 256];
    const int n0 = blockIdx.x * FT_NODES;
    const int nvalid = min(FT_NODES, N_NODES - n0);
    const float4* x4 = (const float4*)(x + (size_t)n0 * CH);
    for (int i = tid; i < nvalid * 16; i += 256) {
        const int n = i >> 4, q = i & 15;
        *(float4*)&xs[n][q * 4] = x4[i];
    }
    __syncthreads();
    if (do_hist) {
        const int st = blockIdx.x * ECHUNK;
        const int en = min(st + ECHUNK, N_EDGES);
        for (int i = st + tid; i < en; i += 256)
            atomicAdd(&lh[((unsigned int)edst[i]) >> 6], 1u);
    }
    const int nl = tid >> 3;
    const int g = tid & 7;
    const int c0 = g * 8;
    const int node = n0 + nl;
    if (nl < nvalid) {
        float acc[8] = {0.f, 0.f, 0.f, 0.f, 0.f, 0.f, 0.f, 0.f};
#pragma unroll
        for (int k = 0; k < 64; ++k) {
            const float xv = xs[nl][k];
            const float4 w0 = *(const float4*)&Ws[k * 64 + c0];
            const float4 w1 = *(const float4*)&Ws[k * 64 + c0 + 4];
            acc[0] = fmaf(xv, w0.x, acc[0]);
            acc[1] = fmaf(xv, w0.y, acc[1]);
            acc[2] = fmaf(xv, w0.z, acc[2]);
            acc[3] = fmaf(xv, w0.w, acc[3]);
            acc[4] = fmaf(xv, w1.x, acc[4]);
            acc[5] = fmaf(xv, w1.y, acc[5]);
            acc[6] = fmaf(xv, w1.z, acc[6]);
            acc[7] = fmaf(xv, w1.w, acc[7]);
        }
        __half2 hv[4];
#pragma unroll
        for (int i = 0; i < 4; ++i) hv[i] = __floats2half2_rn(acc[2 * i], acc[2 * i + 1]);
        *(float4*)(h + (size_t)node * CH + c0) = *(float4*)hv;
        float ps = 0.f, pd = 0.f;
#pragma unroll
        for (int i = 0; i < 8; ++i) {
            ps = fmaf(acc[i], a_src[c0 + i], ps);
            pd = fmaf(acc[i], a_dst[c0 + i], pd);
        }
#pragma unroll
        for (int off = 4; off; off >>= 1) {
            ps += __shfl_xor(ps, off);
            pd += __shfl_xor(pd, off);
        }
        if (g == 0) { ssrc[node] = ps; sdst[node] = pd; }
    }
    if (do_hist) {
        __syncthreads();
        for (int j = tid; j < NB; j += 256)
            hist[(size_t)blockIdx.x * NB + j] = lh[j];
    }
}

// K2: per-bin totals: block b sums hist[*][b].
__global__ __launch_bounds__(256) void k_bintot(
        const unsigned int* __restrict__ hist, unsigned int* __restrict__ bintot) {
    __shared__ unsigned int red[256];
    const int t = threadIdx.x, b = blockIdx.x;
    unsigned int v = 0u;
    for (int c = t; c < NCHK; c += 256) v += hist[(size_t)c * NB + b];
    red[t] = v;
    __syncthreads();
#pragma unroll
    for (int off = 128; off; off >>= 1) {
        if (t < off) red[t] += red[t + off];
        __syncthreads();
    }
    if (t == 0) bintot[b] = red[0];
}

// K3: block b: cb[b] = sum(bintot[0..b)); exclusive-scan column b of hist (+cb[b]).
__global__ __launch_bounds__(256) void k_rewrite(
        const unsigned int* __restrict__ bintot, unsigned int* __restrict__ hist,
        unsigned int* __restrict__ cb) {
    __shared__ unsigned int lcol[NCHK];
    __shared__ unsigned int red[256];
    __shared__ unsigned int sc[256];
    const int t = threadIdx.x, b = blockIdx.x;
    unsigned int v = 0u;
    for (int j = t; j < b; j += 256) v += bintot[j];
    red[t] = v;
    for (int c = t; c < NCHK; c += 256) lcol[c] = hist[(size_t)c * NB + b];
    __syncthreads();
#pragma unroll
    for (int off = 128; off; off >>= 1) {
        if (t < off) red[t] += red[t + off];
        __syncthreads();
    }
    const unsigned int cbb = red[0];
    if (t == 0) { cb[b] = cbb; if (b == NB - 1) cb[NB] = N_EDGES; }
    unsigned int part = 0u;
    const int c0 = 4 * t;
    if (t < 196) {
#pragma unroll
        for (int q = 0; q < 4; ++q) part += lcol[c0 + q];
    }
    sc[t] = part;
    __syncthreads();
#pragma unroll
    for (int off = 1; off < 256; off <<= 1) {
        unsigned int u = (t >= off) ? sc[t - off] : 0u;
        __syncthreads();
        sc[t] += u;
        __syncthreads();
    }
    if (t < 196) {
        unsigned int run = cbb + sc[t] - part;
#pragma unroll
        for (int q = 0; q < 4; ++q) {
            const unsigned int tmp = lcol[c0 + q];
            lcol[c0 + q] = run;
            run += tmp;
        }
    }
    __syncthreads();
    for (int c = t; c < NCHK; c += 256) hist[(size_t)c * NB + b] = lcol[c];
}

// K4: direct scatter (dst<<16|src) via LDS rank counters + precomputed bases.
__global__ __launch_bounds__(256) void k_scatter(
        const int* __restrict__ esrc, const int* __restrict__ edst,
        const unsigned int* __restrict__ hist, unsigned int* __restrict__ buck) {
    __shared__ unsigned int wp[NB];
    const int t = threadIdx.x, blk = blockIdx.x;
    for (int j = t; j < NB; j += 256) wp[j] = hist[(size_t)blk * NB + j];
    __syncthreads();
    const int st = blk * ECHUNK;
    const int en = min(st + ECHUNK, N_EDGES);
    for (int i = st + t; i < en; i += 256) {
        const unsigned int d = (unsigned int)edst[i];
        const unsigned int pos = atomicAdd(&wp[d >> 6], 1u);
        buck[pos] = (d << 16) | (unsigned int)esrc[i];
    }
}

// K5 (fused csr+aggregate): one block per 64-node bucket, 512 threads (8 waves).
// Phase 1: LDS counting sort of the bucket's edges by dst&63 (src ids -> lsrc).
// Phase 2: wave per node (8 nodes/wave serial): w = exp(LeakyReLU(ssrc[s]+sd)),
// dual-edge half2 gather (2 edges/iter, 4-deep ILP), normalize+bias+LeakyReLU(0.3).
__global__ __launch_bounds__(512) void k_csr_agg(
        const unsigned int* __restrict__ buck, const unsigned int* __restrict__ cb,
        const float* __restrict__ ssrc, const float* __restrict__ sdst,
        const __half* __restrict__ h, const float* __restrict__ bias,
        float* __restrict__ out) {
    __shared__ unsigned short lsrc[LCAP];   // 6 KB
    __shared__ unsigned int cnt[64];
    __shared__ unsigned int nb[64];
    __shared__ unsigned int wp[64];
    __shared__ float sdL[64];
    const int t = threadIdx.x, blk = blockIdx.x;
    const int start = (int)cb[blk];
    const int end = (int)cb[blk + 1];
    const int m = end - start;
    if (t < 64) {
        cnt[t] = 0u;
        const int node = blk * 64 + t;
        sdL[t] = (node < N_NODES) ? sdst[node] : 0.f;
    }
    __syncthreads();
    const bool fits = (m <= LCAP);
    if (fits) {
        for (int i = start + t; i < end; i += 512)
            atomicAdd(&cnt[(buck[i] >> 16) & 63u], 1u);
        __syncthreads();
        if (t < 64) {
            const unsigned int own = cnt[t];
            unsigned int incl = own;
#pragma unroll
            for (int d = 1; d < 64; d <<= 1) {
                const unsigned int v = __shfl_up(incl, d);
                if (t >= d) incl += v;
            }
            nb[t] = incl - own;
            wp[t] = incl - own;
        }
        __syncthreads();
        for (int i = start + t; i < end; i += 512) {
            const unsigned int rec = buck[i];
            const unsigned int pos = atomicAdd(&wp[(rec >> 16) & 63u], 1u);
            lsrc[pos] = (unsigned short)(rec & 0xFFFFu);
        }
        __syncthreads();
    }
    const int wid = t >> 6;
    const int lane = t & 63;
    const int slot = lane >> 5;        // 2 edge-slots per wave
    const int c2 = lane & 31;          // channel pair index (ch 2c2, 2c2+1)
    for (int local = wid; local < 64; local += 8) {
        const int node = blk * 64 + local;
        if (node >= N_NODES) continue;
        const float sd = sdL[local];
        float2 acc = make_float2(0.f, 0.f);
        float wsum = 0.f;
        if (fits) {
            const int base = (int)nb[local];
            const int deg = (int)cnt[local];
            for (int tb = 0; tb < deg; tb += 64) {
                const int cnt_t = min(64, deg - tb);
                int s = 0;
                float w = 0.f;
                if (lane < cnt_t) {
                    s = (int)lsrc[base + tb + lane];
                    float e = ssrc[s] + sd;
                    e = (e > 0.f) ? e : 0.2f * e;
                    w = __expf(e);
                }
                wsum += w;
                int j2 = 0;
                for (; j2 + 8 <= cnt_t; j2 += 8) {
                    float a[4]; int si[4]; __half2 hv[4];
#pragma unroll
                    for (int q = 0; q < 4; ++q) {
                        const int e2 = j2 + 2 * q + slot;
                        a[q] = __shfl(w, e2);
                        si[q] = __shfl(s, e2);
                    }
#pragma unroll
                    for (int q = 0; q < 4; ++q)
                        hv[q] = *(const __half2*)&h[(size_t)si[q] * CH + 2 * c2];
#pragma unroll
                    for (int q = 0; q < 4; ++q) {
                        const float2 f2 = __half22float2(hv[q]);
                        acc.x = fmaf(a[q], f2.x, acc.x);
                        acc.y = fmaf(a[q], f2.y, acc.y);
                    }
                }
                for (; j2 < cnt_t; j2 += 2) {
                    const int e2 = j2 + slot;              // e2 <= cnt_t; w=0 beyond deg
                    const float a = __shfl(w, e2);
                    const int si = __shfl(s, e2);
                    const __half2 hv = *(const __half2*)&h[(size_t)si * CH + 2 * c2];
                    const float2 f2 = __half22float2(hv);
                    acc.x = fmaf(a, f2.x, acc.x);
                    acc.y = fmaf(a, f2.y, acc.y);
                }
            }
        } else {   // statistically unreachable fallback: scan whole bucket per node
            for (int i0 = 0; i0 < m; i0 += 64) {
                int s = 0;
                float w = 0.f;
                if (i0 + lane < m) {
                    const unsigned int rec = buck[start + i0 + lane];
                    if ((int)(rec >> 16) == node) {
                        s = (int)(rec & 0xFFFFu);
                        float e = ssrc[s] + sd;
                        e = (e > 0.f) ? e : 0.2f * e;
                        w = __expf(e);
                    }
                }
                wsum += w;
                for (int j2 = 0; j2 < 64; j2 += 2) {
                    const int e2 = j2 + slot;
                    const float a = __shfl(w, e2);
                    const int si = __shfl(s, e2);
                    if (a != 0.f) {
                        const __half2 hv = *(const __half2*)&h[(size_t)si * CH + 2 * c2];
                        const float2 f2 = __half22float2(hv);
                        acc.x = fmaf(a, f2.x, acc.x);
                        acc.y = fmaf(a, f2.y, acc.y);
                    }
                }
            }
        }
        // fold edge-slots, reduce wsum across wave
        acc.x += __shfl_xor(acc.x, 32);
        acc.y += __shfl_xor(acc.y, 32);
#pragma unroll
        for (int off = 32; off; off >>= 1) wsum += __shfl_xor(wsum, off);
        if (lane < 32) {
            const float inv = 1.f / fmaxf(wsum, 1e-9f);
            const float2 bb = *(const float2*)&bias[2 * c2];
            float vx = acc.x * inv + bb.x;
            float vy = acc.y * inv + bb.y;
            vx = (vx > 0.f) ? vx : 0.3f * vx;
            vy = (vy > 0.f) ? vy : 0.3f * vy;
            *(float2*)&out[(size_t)node * CH + 2 * c2] = make_float2(vx, vy);
        }
    }
}

extern "C" void kernel_launch(void* const* d_in, const int* in_sizes, int n_in,
                              void* d_out, int out_size, void* d_ws, size_t ws_size,
                              hipStream_t stream) {
    const float* x     = (const float*)d_in[0];
    const float* W     = (const float*)d_in[1];
    const float* a_src = (const float*)d_in[2];
    const float* a_dst = (const float*)d_in[3];
    const float* b     = (const float*)d_in[4];
    const int* esrc    = (const int*)d_in[5];
    const int* edst    = (const int*)d_in[6];
    float* out = (float*)d_out;

    char* ws = (char*)d_ws;
    __half* h          = (__half*)(ws + OFF_H);
    float* ssrc        = (float*)(ws + OFF_SSRC);
    float* sdst        = (float*)(ws + OFF_SDST);
    unsigned int* hist = (unsigned int*)(ws + OFF_HIST);
    unsigned int* bintot = (unsigned int*)(ws + OFF_BTOT);
    unsigned int* cb   = (unsigned int*)(ws + OFF_CB);
    unsigned int* buck = (unsigned int*)(ws + OFF_BUCK);

    k_feat<<<FT_BLKS, 256, 0, stream>>>(x, W, a_src, a_dst, edst, h, ssrc, sdst, hist);
    k_bintot<<<NB, 256, 0, stream>>>(hist, bintot);
    k_rewrite<<<NB, 256, 0, stream>>>(bintot, hist, cb);
    k_scatter<<<NCHK, 256, 0, stream>>>(esrc, edst, hist, buck);
    k_csr_agg<<<NB, 512, 0, stream>>>(buck, cb, ssrc, sdst, h, b, out);
}

// Round 13
// 77.829 us; speedup vs baseline: 1.2047x; 1.2047x over previous
//
#include <hip/hip_runtime.h>
#include <hip/hip_fp16.h>

#define N_NODES 50000
#define N_EDGES 800000
#define CH 64
#define FT_NODES 32
#define FT_BLKS ((N_NODES + FT_NODES - 1) / FT_NODES)   // 1563
#define NB 782                                          // bins = ceil(N/64) (64-node buckets)
#define NCHK 784                                        // edge chunks (hist blocks in k_feat)
#define ECHUNK ((N_EDGES + NCHK - 1) / NCHK)            // 1021
#define LCAP 2048                                       // k_csr LDS stage cap (mean 1024, sigma 32)

static constexpr size_t alignup16(size_t x) { return (x + 15) & ~(size_t)15; }
// ---------------- ws layout (byte offsets, 16B-aligned) ----------------
static const size_t OFF_H      = 0;                                          // N*CH half (6.4 MB)
static const size_t OFF_SSRC   = alignup16(OFF_H      + (size_t)N_NODES*CH*2);
static const size_t OFF_SDST   = alignup16(OFF_SSRC   + (size_t)N_NODES*4);
static const size_t OFF_HIST   = alignup16(OFF_SDST   + (size_t)N_NODES*4);  // NCHK*NB u32 [chunk][bin]
static const size_t OFF_BTOT   = alignup16(OFF_HIST   + (size_t)NCHK*NB*4);  // NB u32
static const size_t OFF_CB     = alignup16(OFF_BTOT   + (size_t)NB*4);       // NB+1 u32
static const size_t OFF_ROWPTR = alignup16(OFF_CB     + (size_t)(NB+1)*4);   // N+1 i32
static const size_t OFF_BUCK   = alignup16(OFF_ROWPTR + (size_t)(N_NODES+4)*4); // E u32 (3.2 MB)
static const size_t OFF_SPERM  = alignup16(OFF_BUCK   + (size_t)N_EDGES*4);  // E u16 (1.6 MB)

// K1: h = x @ W (fp16 out); s_src/s_dst scores; blocks < NCHK also histogram their
// edge chunk by bin (dst>>6) into LDS -> hist[blk][bin] (coalesced row write).
__global__ __launch_bounds__(256) void k_feat(
        const float* __restrict__ x, const float* __restrict__ W,
        const float* __restrict__ a_src, const float* __restrict__ a_dst,
        const int* __restrict__ edst,
        __half* __restrict__ h, float* __restrict__ ssrc, float* __restrict__ sdst,
        unsigned int* __restrict__ hist) {
    __shared__ float Ws[64 * 64];          // 16 KB
    __shared__ float xs[FT_NODES][68];
    __shared__ unsigned int lh[NB];        // 3.1 KB
    const int tid = threadIdx.x;
    const bool do_hist = (blockIdx.x < NCHK);
    if (do_hist)
        for (int j = tid; j < NB; j += 256) lh[j] = 0u;
#pragma unroll
    for (int i = 0; i < 16; ++i) Ws[tid + i * 256] = W[tid + i * 256];
    const int n0 = blockIdx.x * FT_NODES;
    const int nvalid = min(FT_NODES, N_NODES - n0);
    const float4* x4 = (const float4*)(x + (size_t)n0 * CH);
    for (int i = tid; i < nvalid * 16; i += 256) {
        const int n = i >> 4, q = i & 15;
        *(float4*)&xs[n][q * 4] = x4[i];
    }
    __syncthreads();
    if (do_hist) {
        const int st = blockIdx.x * ECHUNK;
        const int en = min(st + ECHUNK, N_EDGES);
        for (int i = st + tid; i < en; i += 256)
            atomicAdd(&lh[((unsigned int)edst[i]) >> 6], 1u);
    }
    const int nl = tid >> 3;
    const int g = tid & 7;
    const int c0 = g * 8;
    const int node = n0 + nl;
    if (nl < nvalid) {
        float acc[8] = {0.f, 0.f, 0.f, 0.f, 0.f, 0.f, 0.f, 0.f};
#pragma unroll
        for (int k = 0; k < 64; ++k) {
            const float xv = xs[nl][k];
            const float4 w0 = *(const float4*)&Ws[k * 64 + c0];
            const float4 w1 = *(const float4*)&Ws[k * 64 + c0 + 4];
            acc[0] = fmaf(xv, w0.x, acc[0]);
            acc[1] = fmaf(xv, w0.y, acc[1]);
            acc[2] = fmaf(xv, w0.z, acc[2]);
            acc[3] = fmaf(xv, w0.w, acc[3]);
            acc[4] = fmaf(xv, w1.x, acc[4]);
            acc[5] = fmaf(xv, w1.y, acc[5]);
            acc[6] = fmaf(xv, w1.z, acc[6]);
            acc[7] = fmaf(xv, w1.w, acc[7]);
        }
        __half2 hv[4];
#pragma unroll
        for (int i = 0; i < 4; ++i) hv[i] = __floats2half2_rn(acc[2 * i], acc[2 * i + 1]);
        *(float4*)(h + (size_t)node * CH + c0) = *(float4*)hv;
        float ps = 0.f, pd = 0.f;
#pragma unroll
        for (int i = 0; i < 8; ++i) {
            ps = fmaf(acc[i], a_src[c0 + i], ps);
            pd = fmaf(acc[i], a_dst[c0 + i], pd);
        }
#pragma unroll
        for (int off = 4; off; off >>= 1) {
            ps += __shfl_xor(ps, off);
            pd += __shfl_xor(pd, off);
        }
        if (g == 0) { ssrc[node] = ps; sdst[node] = pd; }
    }
    if (do_hist) {
        __syncthreads();
        for (int j = tid; j < NB; j += 256)
            hist[(size_t)blockIdx.x * NB + j] = lh[j];
    }
}

// K2: per-bin totals: block b sums hist[*][b].
__global__ __launch_bounds__(256) void k_bintot(
        const unsigned int* __restrict__ hist, unsigned int* __restrict__ bintot) {
    __shared__ unsigned int red[256];
    const int t = threadIdx.x, b = blockIdx.x;
    unsigned int v = 0u;
    for (int c = t; c < NCHK; c += 256) v += hist[(size_t)c * NB + b];
    red[t] = v;
    __syncthreads();
#pragma unroll
    for (int off = 128; off; off >>= 1) {
        if (t < off) red[t] += red[t + off];
        __syncthreads();
    }
    if (t == 0) bintot[b] = red[0];
}

// K3: block b: cb[b] = sum(bintot[0..b)); exclusive-scan column b of hist (+cb[b]).
__global__ __launch_bounds__(256) void k_rewrite(
        const unsigned int* __restrict__ bintot, unsigned int* __restrict__ hist,
        unsigned int* __restrict__ cb) {
    __shared__ unsigned int lcol[NCHK];
    __shared__ unsigned int red[256];
    __shared__ unsigned int sc[256];
    const int t = threadIdx.x, b = blockIdx.x;
    unsigned int v = 0u;
    for (int j = t; j < b; j += 256) v += bintot[j];
    red[t] = v;
    for (int c = t; c < NCHK; c += 256) lcol[c] = hist[(size_t)c * NB + b];
    __syncthreads();
#pragma unroll
    for (int off = 128; off; off >>= 1) {
        if (t < off) red[t] += red[t + off];
        __syncthreads();
    }
    const unsigned int cbb = red[0];
    if (t == 0) { cb[b] = cbb; if (b == NB - 1) cb[NB] = N_EDGES; }
    unsigned int part = 0u;
    const int c0 = 4 * t;
    if (t < 196) {
#pragma unroll
        for (int q = 0; q < 4; ++q) part += lcol[c0 + q];
    }
    sc[t] = part;
    __syncthreads();
#pragma unroll
    for (int off = 1; off < 256; off <<= 1) {
        unsigned int u = (t >= off) ? sc[t - off] : 0u;
        __syncthreads();
        sc[t] += u;
        __syncthreads();
    }
    if (t < 196) {
        unsigned int run = cbb + sc[t] - part;
#pragma unroll
        for (int q = 0; q < 4; ++q) {
            const unsigned int tmp = lcol[c0 + q];
            lcol[c0 + q] = run;
            run += tmp;
        }
    }
    __syncthreads();
    for (int c = t; c < NCHK; c += 256) hist[(size_t)c * NB + b] = lcol[c];
}

// K4: direct scatter (dst<<16|src) via LDS rank counters + precomputed bases.
__global__ __launch_bounds__(256) void k_scatter(
        const int* __restrict__ esrc, const int* __restrict__ edst,
        const unsigned int* __restrict__ hist, unsigned int* __restrict__ buck) {
    __shared__ unsigned int wp[NB];
    const int t = threadIdx.x, blk = blockIdx.x;
    for (int j = t; j < NB; j += 256) wp[j] = hist[(size_t)blk * NB + j];
    __syncthreads();
    const int st = blk * ECHUNK;
    const int en = min(st + ECHUNK, N_EDGES);
    for (int i = st + t; i < en; i += 256) {
        const unsigned int d = (unsigned int)edst[i];
        const unsigned int pos = atomicAdd(&wp[d >> 6], 1u);
        buck[pos] = (d << 16) | (unsigned int)esrc[i];
    }
}

// K5: one block per 64-node bucket: count by dst&63, wave-shfl scan -> row_ptr;
// sort src ids into LDS, coalesced copy-out.
__global__ __launch_bounds__(256) void k_csr(
        const unsigned int* __restrict__ buck, const unsigned int* __restrict__ cb,
        int* __restrict__ row_ptr, unsigned short* __restrict__ src_perm) {
    __shared__ unsigned int cnt[64];
    __shared__ unsigned int wp[64];
    __shared__ unsigned short lsrc[LCAP];
    const int t = threadIdx.x, blk = blockIdx.x;
    const int start = (int)cb[blk];
    const int end = (int)cb[blk + 1];
    const int m = end - start;
    if (t < 64) cnt[t] = 0u;
    __syncthreads();
    for (int i = start + t; i < end; i += 256)
        atomicAdd(&cnt[(buck[i] >> 16) & 63u], 1u);
    __syncthreads();
    if (t < 64) {
        const unsigned int own = cnt[t];
        unsigned int incl = own;
#pragma unroll
        for (int d = 1; d < 64; d <<= 1) {
            const unsigned int v = __shfl_up(incl, d);
            if (t >= d) incl += v;
        }
        const unsigned int excl = incl - own;
        wp[t] = excl;
        const int node = blk * 64 + t;
        if (node <= N_NODES) row_ptr[node] = start + (int)excl;  // node==N -> E (blk 781)
    }
    __syncthreads();
    if (m <= LCAP) {
        for (int i = start + t; i < end; i += 256) {
            const unsigned int rec = buck[i];
            const unsigned int pos = atomicAdd(&wp[(rec >> 16) & 63u], 1u);
            lsrc[pos] = (unsigned short)(rec & 0xFFFFu);
        }
        __syncthreads();
        for (int p = t; p < m; p += 256)
            src_perm[start + p] = lsrc[p];
    } else {   // statistically unreachable fallback
        for (int i = start + t; i < end; i += 256) {
            const unsigned int rec = buck[i];
            const unsigned int pos = atomicAdd(&wp[(rec >> 16) & 63u], 1u);
            src_perm[start + (int)pos] = (unsigned short)(rec & 0xFFFFu);
        }
    }
}

// K6: per-dst-node CSR gather. Wave = 4 edge-slots x 16 channel-lanes; each lane
// gathers a half4 (8 B) of one edge's h row -> 4 edges / iteration, 4x fewer
// shuffles than scalar. Slot-fold via shfl_xor(16/32); float4 write by lanes 0-15.
__global__ __launch_bounds__(256) void k_node_agg(
        const unsigned short* __restrict__ src_perm, const int* __restrict__ row_ptr,
        const float* __restrict__ ssrc, const float* __restrict__ sdst,
        const __half* __restrict__ h, const float* __restrict__ b,
        float* __restrict__ out) {
    const int tid = threadIdx.x;
    const int lane = tid & 63;
    const int node = blockIdx.x * 4 + (tid >> 6);
    const int row = row_ptr[node];
    const int deg = row_ptr[node + 1] - row;
    const float sd = sdst[node];
    const int slot = lane >> 4;      // edge slot 0..3
    const int c4 = lane & 15;        // channel quad: ch 4*c4 .. 4*c4+3
    float4 acc = make_float4(0.f, 0.f, 0.f, 0.f);
    float wsum = 0.f;
    for (int base = 0; base < deg; base += 64) {
        const int j = base + lane;
        int s = 0;
        float w = 0.f;
        if (j < deg) {
            s = (int)src_perm[row + j];
            float e = ssrc[s] + sd;
            e = (e > 0.f) ? e : 0.2f * e;
            w = __expf(e);
        }
        wsum += w;
        const int cnt_t = min(64, deg - base);
        for (int j2 = 0; j2 < cnt_t; j2 += 16) {   // 4 slots x 4 unroll = 16 edges/iter
            float a[4]; int si[4]; float2 raw[4];
#pragma unroll
            for (int q = 0; q < 4; ++q) {
                const int e = j2 + 4 * q + slot;   // e <= 63 always; w=0 beyond deg
                a[q] = __shfl(w, e);
                si[q] = __shfl(s, e);
            }
#pragma unroll
            for (int q = 0; q < 4; ++q)
                raw[q] = *(const float2*)&h[(size_t)si[q] * CH + 4 * c4];
#pragma unroll
            for (int q = 0; q < 4; ++q) {
                union { float2 f2; __half2 h2[2]; } u;
                u.f2 = raw[q];
                const float2 lo = __half22float2(u.h2[0]);
                const float2 hi = __half22float2(u.h2[1]);
                acc.x = fmaf(a[q], lo.x, acc.x);
                acc.y = fmaf(a[q], lo.y, acc.y);
                acc.z = fmaf(a[q], hi.x, acc.z);
                acc.w = fmaf(a[q], hi.y, acc.w);
            }
        }
    }
    // fold the 4 edge-slots (lanes l, l+16, l+32, l+48 hold the same channels)
    acc.x += __shfl_xor(acc.x, 16); acc.x += __shfl_xor(acc.x, 32);
    acc.y += __shfl_xor(acc.y, 16); acc.y += __shfl_xor(acc.y, 32);
    acc.z += __shfl_xor(acc.z, 16); acc.z += __shfl_xor(acc.z, 32);
    acc.w += __shfl_xor(acc.w, 16); acc.w += __shfl_xor(acc.w, 32);
#pragma unroll
    for (int off = 32; off; off >>= 1) wsum += __shfl_xor(wsum, off);
    if (lane < 16) {
        const float inv = 1.f / fmaxf(wsum, 1e-9f);
        const float4 bb = *(const float4*)&b[4 * c4];
        float vx = acc.x * inv + bb.x;
        float vy = acc.y * inv + bb.y;
        float vz = acc.z * inv + bb.z;
        float vw = acc.w * inv + bb.w;
        vx = (vx > 0.f) ? vx : 0.3f * vx;
        vy = (vy > 0.f) ? vy : 0.3f * vy;
        vz = (vz > 0.f) ? vz : 0.3f * vz;
        vw = (vw > 0.f) ? vw : 0.3f * vw;
        *(float4*)&out[(size_t)node * CH + 4 * c4] = make_float4(vx, vy, vz, vw);
    }
}

extern "C" void kernel_launch(void* const* d_in, const int* in_sizes, int n_in,
                              void* d_out, int out_size, void* d_ws, size_t ws_size,
                              hipStream_t stream) {
    const float* x     = (const float*)d_in[0];
    const float* W     = (const float*)d_in[1];
    const float* a_src = (const float*)d_in[2];
    const float* a_dst = (const float*)d_in[3];
    const float* b     = (const float*)d_in[4];
    const int* esrc    = (const int*)d_in[5];
    const int* edst    = (const int*)d_in[6];
    float* out = (float*)d_out;

    char* ws = (char*)d_ws;
    __half* h                = (__half*)(ws + OFF_H);
    float* ssrc              = (float*)(ws + OFF_SSRC);
    float* sdst              = (float*)(ws + OFF_SDST);
    unsigned int* hist       = (unsigned int*)(ws + OFF_HIST);
    unsigned int* bintot     = (unsigned int*)(ws + OFF_BTOT);
    unsigned int* cb         = (unsigned int*)(ws + OFF_CB);
    int* row_ptr             = (int*)(ws + OFF_ROWPTR);
    unsigned int* buck       = (unsigned int*)(ws + OFF_BUCK);
    unsigned short* src_perm = (unsigned short*)(ws + OFF_SPERM);

    k_feat<<<FT_BLKS, 256, 0, stream>>>(x, W, a_src, a_dst, edst, h, ssrc, sdst, hist);
    k_bintot<<<NB, 256, 0, stream>>>(hist, bintot);
    k_rewrite<<<NB, 256, 0, stream>>>(bintot, hist, cb);
    k_scatter<<<NCHK, 256, 0, stream>>>(esrc, edst, hist, buck);
    k_csr<<<NB, 256, 0, stream>>>(buck, cb, row_ptr, src_perm);
    k_node_agg<<<N_NODES / 4, 256, 0, stream>>>(src_perm, row_ptr, ssrc, sdst, h, b, out);
}

// Round 14
// 73.531 us; speedup vs baseline: 1.2751x; 1.0585x over previous
//
#include <hip/hip_runtime.h>
#include <hip/hip_fp16.h>

#define N_NODES 50000
#define N_EDGES 800000
#define CH 64
#define FT_NODES 64
#define FT_BLKS ((N_NODES + FT_NODES - 1) / FT_NODES)   // 782
#define NB 782                                          // bins = ceil(N/64) (64-node buckets)
#define NCHK 782                                        // edge chunks == FT_BLKS
#define ECHUNK ((N_EDGES + NCHK - 1) / NCHK)            // 1024
#define LCAP 2048                                       // k_csr LDS stage cap (mean 1024, sigma 32)

static constexpr size_t alignup16(size_t x) { return (x + 15) & ~(size_t)15; }
// ---------------- ws layout (byte offsets, 16B-aligned) ----------------
static const size_t OFF_H      = 0;                                          // N*CH half (6.4 MB)
static const size_t OFF_SSRC   = alignup16(OFF_H      + (size_t)N_NODES*CH*2);
static const size_t OFF_SDST   = alignup16(OFF_SSRC   + (size_t)N_NODES*4);
static const size_t OFF_HIST   = alignup16(OFF_SDST   + (size_t)N_NODES*4);  // NCHK*NB u32 [chunk][bin]
static const size_t OFF_BTOT   = alignup16(OFF_HIST   + (size_t)NCHK*NB*4);  // NB u32
static const size_t OFF_CB     = alignup16(OFF_BTOT   + (size_t)NB*4);       // NB+1 u32
static const size_t OFF_ROWPTR = alignup16(OFF_CB     + (size_t)(NB+1)*4);   // N+1 i32
static const size_t OFF_BUCK   = alignup16(OFF_ROWPTR + (size_t)(N_NODES+4)*4); // E u32 (3.2 MB)
static const size_t OFF_SPERM  = alignup16(OFF_BUCK   + (size_t)N_EDGES*4);  // E u16 (1.6 MB)

// K1: h = x @ W (fp16 out); scores; per-block edge-chunk histogram (dst>>6) -> hist[blk][bin].
// 2 nodes per thread: one pair of W ds_read_b128 feeds 16 FMAs (2x LDS efficiency).
__global__ __launch_bounds__(256) void k_feat(
        const float* __restrict__ x, const float* __restrict__ W,
        const float* __restrict__ a_src, const float* __restrict__ a_dst,
        const int* __restrict__ edst,
        __half* __restrict__ h, float* __restrict__ ssrc, float* __restrict__ sdst,
        unsigned int* __restrict__ hist) {
    __shared__ float Ws[64 * 64];          // 16 KB
    __shared__ float xs[FT_NODES][68];     // 17.4 KB, pad 64->68
    __shared__ unsigned int lh[NB];        // 3.1 KB
    const int tid = threadIdx.x;
    for (int j = tid; j < NB; j += 256) lh[j] = 0u;
#pragma unroll
    for (int i = 0; i < 16; ++i) Ws[tid + i * 256] = W[tid + i * 256];
    const int n0 = blockIdx.x * FT_NODES;
    const int nvalid = min(FT_NODES, N_NODES - n0);
    const float4* x4 = (const float4*)(x + (size_t)n0 * CH);
    for (int i = tid; i < nvalid * 16; i += 256) {
        const int n = i >> 4, q = i & 15;
        *(float4*)&xs[n][q * 4] = x4[i];
    }
    __syncthreads();
    {   // histogram this block's edge chunk (LDS-only atomics)
        const int st = blockIdx.x * ECHUNK;
        const int en = min(st + ECHUNK, N_EDGES);
        for (int i = st + tid; i < en; i += 256)
            atomicAdd(&lh[((unsigned int)edst[i]) >> 6], 1u);
    }
    const int nl = tid >> 3;          // node-pair index 0..31
    const int g = tid & 7;
    const int c0 = g * 8;
    const int nodeA = n0 + 2 * nl;
    const bool vA = (2 * nl < nvalid);
    const bool vB = (2 * nl + 1 < nvalid);
    float accA[8] = {0,0,0,0,0,0,0,0};
    float accB[8] = {0,0,0,0,0,0,0,0};
#pragma unroll
    for (int k = 0; k < 64; ++k) {
        const float xv0 = xs[2 * nl][k];
        const float xv1 = xs[2 * nl + 1][k];
        const float4 w0 = *(const float4*)&Ws[k * 64 + c0];
        const float4 w1 = *(const float4*)&Ws[k * 64 + c0 + 4];
        accA[0] = fmaf(xv0, w0.x, accA[0]); accB[0] = fmaf(xv1, w0.x, accB[0]);
        accA[1] = fmaf(xv0, w0.y, accA[1]); accB[1] = fmaf(xv1, w0.y, accB[1]);
        accA[2] = fmaf(xv0, w0.z, accA[2]); accB[2] = fmaf(xv1, w0.z, accB[2]);
        accA[3] = fmaf(xv0, w0.w, accA[3]); accB[3] = fmaf(xv1, w0.w, accB[3]);
        accA[4] = fmaf(xv0, w1.x, accA[4]); accB[4] = fmaf(xv1, w1.x, accB[4]);
        accA[5] = fmaf(xv0, w1.y, accA[5]); accB[5] = fmaf(xv1, w1.y, accB[5]);
        accA[6] = fmaf(xv0, w1.z, accA[6]); accB[6] = fmaf(xv1, w1.z, accB[6]);
        accA[7] = fmaf(xv0, w1.w, accA[7]); accB[7] = fmaf(xv1, w1.w, accB[7]);
    }
    float psA = 0.f, pdA = 0.f, psB = 0.f, pdB = 0.f;
#pragma unroll
    for (int i = 0; i < 8; ++i) {
        const float as = a_src[c0 + i], ad = a_dst[c0 + i];
        psA = fmaf(accA[i], as, psA); pdA = fmaf(accA[i], ad, pdA);
        psB = fmaf(accB[i], as, psB); pdB = fmaf(accB[i], ad, pdB);
    }
#pragma unroll
    for (int off = 4; off; off >>= 1) {
        psA += __shfl_xor(psA, off); pdA += __shfl_xor(pdA, off);
        psB += __shfl_xor(psB, off); pdB += __shfl_xor(pdB, off);
    }
    if (vA) {
        __half2 hv[4];
#pragma unroll
        for (int i = 0; i < 4; ++i) hv[i] = __floats2half2_rn(accA[2 * i], accA[2 * i + 1]);
        *(float4*)(h + (size_t)nodeA * CH + c0) = *(float4*)hv;
        if (g == 0) { ssrc[nodeA] = psA; sdst[nodeA] = pdA; }
    }
    if (vB) {
        __half2 hv[4];
#pragma unroll
        for (int i = 0; i < 4; ++i) hv[i] = __floats2half2_rn(accB[2 * i], accB[2 * i + 1]);
        *(float4*)(h + (size_t)(nodeA + 1) * CH + c0) = *(float4*)hv;
        if (g == 0) { ssrc[nodeA + 1] = psB; sdst[nodeA + 1] = pdB; }
    }
    __syncthreads();
    for (int j = tid; j < NB; j += 256)
        hist[(size_t)blockIdx.x * NB + j] = lh[j];
}

// K2: per-bin totals: block b sums hist[*][b].
__global__ __launch_bounds__(256) void k_bintot(
        const unsigned int* __restrict__ hist, unsigned int* __restrict__ bintot) {
    __shared__ unsigned int red[256];
    const int t = threadIdx.x, b = blockIdx.x;
    unsigned int v = 0u;
    for (int c = t; c < NCHK; c += 256) v += hist[(size_t)c * NB + b];
    red[t] = v;
    __syncthreads();
#pragma unroll
    for (int off = 128; off; off >>= 1) {
        if (t < off) red[t] += red[t + off];
        __syncthreads();
    }
    if (t == 0) bintot[b] = red[0];
}

// K3: block b: cb[b] = sum(bintot[0..b)); exclusive-scan column b of hist (+cb[b]).
__global__ __launch_bounds__(256) void k_rewrite(
        const unsigned int* __restrict__ bintot, unsigned int* __restrict__ hist,
        unsigned int* __restrict__ cb) {
    __shared__ unsigned int lcol[784];     // NCHK padded to 196*4
    __shared__ unsigned int red[256];
    __shared__ unsigned int sc[256];
    const int t = threadIdx.x, b = blockIdx.x;
    unsigned int v = 0u;
    for (int j = t; j < b; j += 256) v += bintot[j];
    red[t] = v;
    for (int c = t; c < 784; c += 256) lcol[c] = (c < NCHK) ? hist[(size_t)c * NB + b] : 0u;
    __syncthreads();
#pragma unroll
    for (int off = 128; off; off >>= 1) {
        if (t < off) red[t] += red[t + off];
        __syncthreads();
    }
    const unsigned int cbb = red[0];
    if (t == 0) { cb[b] = cbb; if (b == NB - 1) cb[NB] = N_EDGES; }
    unsigned int part = 0u;
    const int c0 = 4 * t;
    if (t < 196) {
#pragma unroll
        for (int q = 0; q < 4; ++q) part += lcol[c0 + q];
    }
    sc[t] = part;
    __syncthreads();
#pragma unroll
    for (int off = 1; off < 256; off <<= 1) {
        unsigned int u = (t >= off) ? sc[t - off] : 0u;
        __syncthreads();
        sc[t] += u;
        __syncthreads();
    }
    if (t < 196) {
        unsigned int run = cbb + sc[t] - part;
#pragma unroll
        for (int q = 0; q < 4; ++q) {
            const unsigned int tmp = lcol[c0 + q];
            lcol[c0 + q] = run;
            run += tmp;
        }
    }
    __syncthreads();
    for (int c = t; c < NCHK; c += 256) hist[(size_t)c * NB + b] = lcol[c];
}

// K4: direct scatter (dst<<16|src) via LDS rank counters + precomputed bases.
__global__ __launch_bounds__(256) void k_scatter(
        const int* __restrict__ esrc, const int* __restrict__ edst,
        const unsigned int* __restrict__ hist, unsigned int* __restrict__ buck) {
    __shared__ unsigned int wp[NB];
    const int t = threadIdx.x, blk = blockIdx.x;
    for (int j = t; j < NB; j += 256) wp[j] = hist[(size_t)blk * NB + j];
    __syncthreads();
    const int st = blk * ECHUNK;
    const int en = min(st + ECHUNK, N_EDGES);
    for (int i = st + t; i < en; i += 256) {
        const unsigned int d = (unsigned int)edst[i];
        const unsigned int pos = atomicAdd(&wp[d >> 6], 1u);
        buck[pos] = (d << 16) | (unsigned int)esrc[i];
    }
}

// K5: one block per 64-node bucket: count by dst&63, wave-shfl scan -> row_ptr;
// sort src ids into LDS, coalesced copy-out.
__global__ __launch_bounds__(256) void k_csr(
        const unsigned int* __restrict__ buck, const unsigned int* __restrict__ cb,
        int* __restrict__ row_ptr, unsigned short* __restrict__ src_perm) {
    __shared__ unsigned int cnt[64];
    __shared__ unsigned int wp[64];
    __shared__ unsigned short lsrc[LCAP];
    const int t = threadIdx.x, blk = blockIdx.x;
    const int start = (int)cb[blk];
    const int end = (int)cb[blk + 1];
    const int m = end - start;
    if (t < 64) cnt[t] = 0u;
    __syncthreads();
    for (int i = start + t; i < end; i += 256)
        atomicAdd(&cnt[(buck[i] >> 16) & 63u], 1u);
    __syncthreads();
    if (t < 64) {
        const unsigned int own = cnt[t];
        unsigned int incl = own;
#pragma unroll
        for (int d = 1; d < 64; d <<= 1) {
            const unsigned int v = __shfl_up(incl, d);
            if (t >= d) incl += v;
        }
        const unsigned int excl = incl - own;
        wp[t] = excl;
        const int node = blk * 64 + t;
        if (node <= N_NODES) row_ptr[node] = start + (int)excl;  // node==N -> E (blk 781)
    }
    __syncthreads();
    if (m <= LCAP) {
        for (int i = start + t; i < end; i += 256) {
            const unsigned int rec = buck[i];
            const unsigned int pos = atomicAdd(&wp[(rec >> 16) & 63u], 1u);
            lsrc[pos] = (unsigned short)(rec & 0xFFFFu);
        }
        __syncthreads();
        for (int p = t; p < m; p += 256)
            src_perm[start + p] = lsrc[p];
    } else {   // statistically unreachable fallback
        for (int i = start + t; i < end; i += 256) {
            const unsigned int rec = buck[i];
            const unsigned int pos = atomicAdd(&wp[(rec >> 16) & 63u], 1u);
            src_perm[start + (int)pos] = (unsigned short)(rec & 0xFFFFu);
        }
    }
}

// K6: CSR gather, 2 nodes per wave (half = lane>>5), 2 edge-slots x 16 channel
// lanes per node; 8 half4 gathers in flight per lane -> 2 independent latency
// chains per wave. Slot-fold shfl_xor(16); float4 write by hl<16 of each half.
__global__ __launch_bounds__(256) void k_node_agg(
        const unsigned short* __restrict__ src_perm, const int* __restrict__ row_ptr,
        const float* __restrict__ ssrc, const float* __restrict__ sdst,
        const __half* __restrict__ h, const float* __restrict__ b,
        float* __restrict__ out) {
    const int tid = threadIdx.x;
    const int lane = tid & 63;
    const int wid = tid >> 6;
    const int half = lane >> 5;
    const int hl = lane & 31;
    const int slot = hl >> 4;        // edge slot 0..1
    const int c4 = hl & 15;          // channel quad
    const int node = blockIdx.x * 8 + wid * 2 + half;   // 6250*8 = 50000 exact
    const int row = row_ptr[node];
    const int deg = row_ptr[node + 1] - row;
    const float sd = sdst[node];
    const int degmax = max(deg, __shfl_xor(deg, 32));
    float4 acc = make_float4(0.f, 0.f, 0.f, 0.f);
    float wsum = 0.f;
    for (int base = 0; base < degmax; base += 32) {
        const int j = base + hl;
        int s = 0;
        float w = 0.f;
        if (j < deg) {
            s = (int)src_perm[row + j];
            float e = ssrc[s] + sd;
            e = (e > 0.f) ? e : 0.2f * e;
            w = __expf(e);
        }
        wsum += w;
        const int cnt_t = min(32, degmax - base);
        for (int j2 = 0; j2 < cnt_t; j2 += 16) {   // 16 edges per step (8q x 2slot)
            float a[8]; int si[8]; float2 raw[8];
#pragma unroll
            for (int q = 0; q < 8; ++q) {
                const int srcl = half * 32 + j2 + 2 * q + slot;   // own half's lanes
                a[q] = __shfl(w, srcl);
                si[q] = __shfl(s, srcl);
            }
#pragma unroll
            for (int q = 0; q < 8; ++q)
                raw[q] = *(const float2*)&h[(size_t)si[q] * CH + 4 * c4];
#pragma unroll
            for (int q = 0; q < 8; ++q) {
                union { float2 f2; __half2 h2[2]; } u;
                u.f2 = raw[q];
                const float2 lo = __half22float2(u.h2[0]);
                const float2 hi = __half22float2(u.h2[1]);
                acc.x = fmaf(a[q], lo.x, acc.x);
                acc.y = fmaf(a[q], lo.y, acc.y);
                acc.z = fmaf(a[q], hi.x, acc.z);
                acc.w = fmaf(a[q], hi.y, acc.w);
            }
        }
    }
    // fold the 2 edge-slots (hl and hl^16, stays within the 32-lane half)
    acc.x += __shfl_xor(acc.x, 16);
    acc.y += __shfl_xor(acc.y, 16);
    acc.z += __shfl_xor(acc.z, 16);
    acc.w += __shfl_xor(acc.w, 16);
#pragma unroll
    for (int off = 16; off; off >>= 1) wsum += __shfl_xor(wsum, off);
    if (hl < 16) {
        const float inv = 1.f / fmaxf(wsum, 1e-9f);
        const float4 bb = *(const float4*)&b[4 * c4];
        float vx = acc.x * inv + bb.x;
        float vy = acc.y * inv + bb.y;
        float vz = acc.z * inv + bb.z;
        float vw = acc.w * inv + bb.w;
        vx = (vx > 0.f) ? vx : 0.3f * vx;
        vy = (vy > 0.f) ? vy : 0.3f * vy;
        vz = (vz > 0.f) ? vz : 0.3f * vz;
        vw = (vw > 0.f) ? vw : 0.3f * vw;
        *(float4*)&out[(size_t)node * CH + 4 * c4] = make_float4(vx, vy, vz, vw);
    }
}

extern "C" void kernel_launch(void* const* d_in, const int* in_sizes, int n_in,
                              void* d_out, int out_size, void* d_ws, size_t ws_size,
                              hipStream_t stream) {
    const float* x     = (const float*)d_in[0];
    const float* W     = (const float*)d_in[1];
    const float* a_src = (const float*)d_in[2];
    const float* a_dst = (const float*)d_in[3];
    const float* b     = (const float*)d_in[4];
    const int* esrc    = (const int*)d_in[5];
    const int* edst    = (const int*)d_in[6];
    float* out = (float*)d_out;

    char* ws = (char*)d_ws;
    __half* h                = (__half*)(ws + OFF_H);
    float* ssrc              = (float*)(ws + OFF_SSRC);
    float* sdst              = (float*)(ws + OFF_SDST);
    unsigned int* hist       = (unsigned int*)(ws + OFF_HIST);
    unsigned int* bintot     = (unsigned int*)(ws + OFF_BTOT);
    unsigned int* cb         = (unsigned int*)(ws + OFF_CB);
    int* row_ptr             = (int*)(ws + OFF_ROWPTR);
    unsigned int* buck       = (unsigned int*)(ws + OFF_BUCK);
    unsigned short* src_perm = (unsigned short*)(ws + OFF_SPERM);

    k_feat<<<FT_BLKS, 256, 0, stream>>>(x, W, a_src, a_dst, edst, h, ssrc, sdst, hist);
    k_bintot<<<NB, 256, 0, stream>>>(hist, bintot);
    k_rewrite<<<NB, 256, 0, stream>>>(bintot, hist, cb);
    k_scatter<<<NCHK, 256, 0, stream>>>(esrc, edst, hist, buck);
    k_csr<<<NB, 256, 0, stream>>>(buck, cb, row_ptr, src_perm);
    k_node_agg<<<N_NODES / 8, 256, 0, stream>>>(src_perm, row_ptr, ssrc, sdst, h, b, out);
}